// Round 8
// baseline (7681.413 us; speedup 1.0000x reference)
//
#include <hip/hip_runtime.h>
#include <stdint.h>

typedef __attribute__((ext_vector_type(4))) float f32x4;
typedef __attribute__((ext_vector_type(2))) unsigned int u32x2;
typedef __attribute__((ext_vector_type(4))) unsigned int u32x4;

#define T_STEPS 4096
#define HID 1024
#define NBLK 256
#define NREP 8          // mailbox replicas (R5-proven knee; 16 regressed)

static __device__ __forceinline__ float u2f(unsigned int u) {
    union { float f; unsigned int i; } c; c.i = u; return c.f;
}
static __device__ __forceinline__ unsigned int f2u(float f) {
    union { float f; unsigned int i; } c; c.f = f; return c.i;
}

// ---------------------------------------------------------------------------
// Fully fused persistent LSTM, fp32. 256 blocks x 256 threads, 1 block/CU.
//
// Structure (R7, 7.18 ms): PER-WAVE UNITS + INTRA-WAVE REDUCE.
// Wave w of block b owns hidden unit (b*4+w) = all 4 gate columns
//   col(g) = g*1024 + b*4 + w.  Lane l: g = l&3, seg = l>>2;
//   thread holds U/W[64*seg .. +64)[col(g)] in VGPRs (64 each).
// Cross-column reduction: 4x shfl_xor — no red[] LDS, no S1. One barrier
// per step (S2). All 4 waves compute gates & publish their own unit in
// parallel: lanes 0-7 -> 8 replicas.
//
// R8 vs R7 — ONE theory: the poll's vmcnt(0) was waiting on FOREIGN VMEM.
//  * The x_{t+3} prefetch (HBM stream, ~900 cy) was issued at E, BEFORE the
//    poll; every round-1 vmcnt(0) waited for it => up to ~600 cy/step of
//    hidden stall. Moved to AFTER the poll (post-H); consumed at E(t+1)
//    with ~700 cy slack. (Poll asm's "memory" clobber pins it there.)
//  * The publish store ack (~RT/2) was also drained inside round 1. A
//    standalone s_waitcnt vmcnt(0) BEFORE the poll loop (after F's ~260 cy
//    of FMAs) drains it nearly for free; each poll round's vmcnt(0) now
//    covers only its own 2 loads.
//
// SINGLE-HOP mailbox, 8x replicated. Pair {f32 h, u32 tag=t+1}, one
// global_store_dwordx2 sc0 sc1 per lane (8 B aligned => single-copy
// atomic; tag arrival == data arrival).
// Poll: ONE asm block per round (issue + vmcnt(0) + check) — R1/R3 proved
// split-asm register lifetimes corrupt data; nothing in flight at exit.
//
// Buffering (no S1 => cross-wave LDS needs parity separation):
//  * h_lds[2][.]: A(t) reads h_t from h_lds[p]; H(t) stages h_{t+1} into
//    h_lds[nxt]. Disjoint within an iter; S2 covers cross-iter.
//  * x_lds[2][.]: F(t) reads x_{t+1} from x_lds[nxt] (staged at E(t-1),
//    S2-covered); E(t) writes x_{t+2} into the DEAD buffer x_lds[p].
//    xpre (x_{t+3}) is loaded post-poll at iter t.
//
// Mailbox parity-2 safety WITHOUT S1: thread tid polls units 4tid..4tid+3
// — i.e. ALL FOUR WAVES of block tid. Any poll success at tag t+1 implies
// every wave of every block passed publish(t+1), hence (program order)
// passed its poll(t) = consumed parity-p tags t. Overwrites (at t+2) thus
// always follow global consumption (at t). Tags monotonic; poll uses >=.
// Workspace: 8*2*1024 u64 = 128 KB, zeroed.
//
// out rows 0..4094: rotating block (t & 255) writes the full coalesced row
// from poll registers. Row 4095 + h_T + c_T: lane 0 of each wave.
// ---------------------------------------------------------------------------
__global__ __launch_bounds__(256, 1) void lstm_fused(
    const float* __restrict__ x,    // [4096,1024]
    const float* __restrict__ W,    // [1024,4096]
    const float* __restrict__ U,    // [1024,4096]
    const float* __restrict__ bias, // [4096]
    float* __restrict__ out,        // [4096*1024 + 1024 + 1024]
    unsigned long long* __restrict__ pairs) // [8][2][1024] {f32,u32}, zeroed
{
    const int tid  = threadIdx.x;
    const int b    = blockIdx.x;
    const int w    = tid >> 6;      // wave index = unit sub-index
    const int l    = tid & 63;
    const int g    = l & 3;         // gate index (i,f,g,o)
    const int seg  = l >> 2;        // h-segment [64*seg, 64*seg+64)
    const int col  = g * 1024 + b * 4 + w;
    const int unit = b * 4 + w;

    __shared__ __align__(16) float h_lds[2][16 * 68];  // h[k] at [par][ (k>>6)*68 + (k&63) ]
    __shared__ __align__(16) float x_lds[2][16 * 68];
    __shared__ __align__(16) float bias_l[16];         // [g*4 + u]

    float Ureg[64], Wreg[64];
    #pragma unroll
    for (int i = 0; i < 64; ++i) {
        const size_t r = (size_t)(seg * 64 + i) * 4096 + col;
        Ureg[i] = U[r];
        Wreg[i] = W[r];
    }
    if (tid < 16) bias_l[tid] = bias[(tid >> 2) * 1024 + b * 4 + (tid & 3)];

    for (int i = tid; i < 2 * 16 * 68; i += 256) ((float*)h_lds)[i] = 0.0f; // h0 = 0
    const int xofs = (tid >> 4) * 68 + (tid & 15) * 4;  // slot of elems [4tid,4tid+4)
    *(f32x4*)&x_lds[0][xofs] = *(const f32x4*)(x + (size_t)tid * 4);          // x_0
    *(f32x4*)&x_lds[1][xofs] = *(const f32x4*)(x + 1024 + (size_t)tid * 4);   // x_1
    f32x4 xpre = *(const f32x4*)(x + 2048 + (size_t)tid * 4);                 // x_2
    __syncthreads();

    const int hbase = seg * 68;

    // prologue: acc_x = W.x_0 partials (4 independent FMA chains)
    float acc_x;
    {
        float b0 = 0.f, b1 = 0.f, b2 = 0.f, b3 = 0.f;
        #pragma unroll
        for (int i = 0; i < 16; ++i) {
            f32x4 x4 = *(const f32x4*)&x_lds[0][hbase + 4 * i];
            b0 += x4.x * Wreg[4*i];   b1 += x4.y * Wreg[4*i+1];
            b2 += x4.z * Wreg[4*i+2]; b3 += x4.w * Wreg[4*i+3];
        }
        acc_x = (b0 + b1) + (b2 + b3);
    }

    float c_reg = 0.0f;   // cell state of unit (b*4+w), replicated on all lanes

    for (int t = 0; t < T_STEPS; ++t) {
        const int p   = t & 1;
        const int nxt = (t + 1) & 1;

        // A: acc = W.x_t (precomputed) + U.h_t partial
        float acc;
        {
            float a0 = 0.f, a1 = 0.f, a2 = 0.f, a3 = 0.f;
            #pragma unroll
            for (int i = 0; i < 16; ++i) {
                f32x4 h4 = *(const f32x4*)&h_lds[p][hbase + 4 * i];
                a0 += h4.x * Ureg[4*i];   a1 += h4.y * Ureg[4*i+1];
                a2 += h4.z * Ureg[4*i+2]; a3 += h4.w * Ureg[4*i+3];
            }
            acc = acc_x + ((a0 + a1) + (a2 + a3));
        }

        // B: intra-wave reduce over the 16 segs (lanes sharing l&3)
        acc += __shfl_xor(acc, 4);
        acc += __shfl_xor(acc, 8);
        acc += __shfl_xor(acc, 16);
        acc += __shfl_xor(acc, 32);
        // lanes l ≡ g (mod 4) now hold the full sum for gate g

        // C: gates (all 64 lanes, redundant — keeps c_reg wave-replicated)
        const float gi = __shfl(acc, 0) + bias_l[0 + w];
        const float gf = __shfl(acc, 1) + bias_l[4 + w];
        const float gg = __shfl(acc, 2) + bias_l[8 + w];
        const float go = __shfl(acc, 3) + bias_l[12 + w];
        const float iv = 1.0f / (1.0f + __expf(-gi));
        const float fv = 1.0f / (1.0f + __expf(-gf));
        const float tg = 1.0f - 2.0f / (1.0f + __expf(2.0f * gg));
        const float ov = 1.0f / (1.0f + __expf(-go));
        const float cn = fv * c_reg + iv * tg;
        c_reg = cn;
        const float hn = ov * (1.0f - 2.0f / (1.0f + __expf(2.0f * cn)));

        if (t == T_STEPS - 1) {
            if (l == 0) {
                out[(size_t)t * HID + unit] = hn;                 // row 4095
                out[(size_t)T_STEPS * HID + unit] = hn;           // h_T
                out[(size_t)T_STEPS * HID + HID + unit] = cn;     // c_T
            }
            break;
        }

        // D: publish — lane r (r<8) stores unit's pair into replica r
        if (l < NREP) {
            u32x2 pr;
            pr.x = f2u(hn);
            pr.y = (unsigned int)(t + 1);
            unsigned long long* pp = pairs + (size_t)l * 2048
                                   + (size_t)p * 1024 + unit;
            asm volatile("global_store_dwordx2 %0, %1, off sc0 sc1"
                         :: "v"(pp), "v"(pr) : "memory");
        }

        // E: write x_{t+2} (loaded last iter) into dead buffer x_lds[p].
        //    NOTE: no global load here anymore — keeps the poll rounds pure.
        *(f32x4*)&x_lds[p][xofs] = xpre;

        // F: acc_x = W.x_{t+1} (overlaps publish flight; reads x_lds[nxt],
        //    staged at E(t-1) and S2-covered)
        {
            float b0 = 0.f, b1 = 0.f, b2 = 0.f, b3 = 0.f;
            #pragma unroll
            for (int i = 0; i < 16; ++i) {
                f32x4 x4 = *(const f32x4*)&x_lds[nxt][hbase + 4 * i];
                b0 += x4.x * Wreg[4*i];   b1 += x4.y * Wreg[4*i+1];
                b2 += x4.z * Wreg[4*i+2]; b3 += x4.w * Wreg[4*i+3];
            }
            acc_x = (b0 + b1) + (b2 + b3);
        }

        // Pre-poll drain: retire the publish-store ack (mostly elapsed under
        // E+F) so every poll round's vmcnt(0) covers ONLY its own 2 loads.
        asm volatile("s_waitcnt vmcnt(0)" ::: "memory");

        // G: poll own 4 pairs (units 4tid..4tid+3) from replica (b & 7).
        //    ONE asm block per round; nothing in flight at exit.
        f32x4 hv4;
        {
            const unsigned int want = (unsigned int)(t + 1);
            const unsigned long long* pp = pairs + (size_t)(b & 7) * 2048
                                         + (size_t)p * 1024 + tid * 4;
            u32x4 q0, q1;
            for (;;) {
                asm volatile("global_load_dwordx4 %0, %2, off sc0 sc1\n\t"
                             "global_load_dwordx4 %1, %3, off sc0 sc1\n\t"
                             "s_waitcnt vmcnt(0)"
                             : "=&v"(q0), "=&v"(q1)
                             : "v"(pp), "v"(pp + 2) : "memory");
                if (q0.y >= want && q0.w >= want && q1.y >= want && q1.w >= want)
                    break;
            }
            hv4.x = u2f(q0.x); hv4.y = u2f(q0.z);
            hv4.z = u2f(q1.x); hv4.w = u2f(q1.z);
        }

        // H: rotating writer emits coalesced out row t; stage h_{t+1}
        if (b == (t & 255))
            *(f32x4*)(out + (size_t)t * HID + tid * 4) = hv4;
        *(f32x4*)&h_lds[nxt][xofs] = hv4;

        // xpre prefetch for x_{t+3}: issued POST-poll (was at E). Consumed
        // at E(t+1) with ~700 cy of slack; compiler's waitcnt before that
        // ds_write covers it. The poll asm's "memory" clobber prevents the
        // compiler hoisting this load above the poll.
        {
            const int tp3 = (t + 3 < T_STEPS) ? (t + 3) : (T_STEPS - 1);
            xpre = *(const f32x4*)(x + (size_t)tp3 * 1024 + tid * 4);
        }

        __syncthreads();   // [S2] h_lds[nxt] + x_lds[p] staged (ONLY barrier)
    }
}

extern "C" void kernel_launch(void* const* d_in, const int* in_sizes, int n_in,
                              void* d_out, int out_size, void* d_ws, size_t ws_size,
                              hipStream_t stream) {
    const float* x    = (const float*)d_in[0];
    const float* W    = (const float*)d_in[1];
    const float* U    = (const float*)d_in[2];
    const float* bias = (const float*)d_in[3];
    float* out = (float*)d_out;

    // Workspace: pairs[8][2][1024] x 8 B = 128 KB @ +0 (zeroed: tag fields
    // must start below 1; re-poisoned 0xAA would read as huge tags).
    unsigned long long* pairs = (unsigned long long*)d_ws;

    hipMemsetAsync(pairs, 0, (size_t)NREP * 2 * 1024 * sizeof(unsigned long long), stream);
    lstm_fused<<<NBLK, 256, 0, stream>>>(x, W, U, bias, out, pairs);
}

// Round 9
// 7190.535 us; speedup vs baseline: 1.0683x; 1.0683x over previous
//
#include <hip/hip_runtime.h>
#include <stdint.h>

typedef __attribute__((ext_vector_type(4))) float f32x4;
typedef __attribute__((ext_vector_type(2))) unsigned int u32x2;
typedef __attribute__((ext_vector_type(4))) unsigned int u32x4;

#define T_STEPS 4096
#define HID 1024
#define NBLK 256
#define NREP 8          // mailbox replicas (R5-proven knee; 16 regressed)

static __device__ __forceinline__ float u2f(unsigned int u) {
    union { float f; unsigned int i; } c; c.i = u; return c.f;
}
static __device__ __forceinline__ unsigned int f2u(float f) {
    union { float f; unsigned int i; } c; c.f = f; return c.i;
}

// ---------------------------------------------------------------------------
// Fully fused persistent LSTM, fp32. 256 blocks x 256 threads, 1 block/CU.
//
// Structure (R7, 7.18 ms): PER-WAVE UNITS + INTRA-WAVE REDUCE.
// Wave w of block b owns hidden unit (b*4+w) = all 4 gate columns
//   col(g) = g*1024 + b*4 + w.  Lane l: g = l&3, seg = l>>2;
//   thread holds U/W[64*seg .. +64)[col(g)] in VGPRs (64 each).
// Cross-column reduction: 4x shfl_xor — no red[] LDS, no S1. One barrier
// per step (S2). All 4 waves compute gates & publish their own unit in
// parallel: lanes 0-7 -> 8 replicas.
//
// R9 vs R7 — ONE change: KILL THE ROTATING-WRITER STRAGGLER.
// R7's block (t & 255) wrote the full 4 KB out row AFTER the poll; S2's
// implicit vmcnt(0)-before-barrier made that block eat the store ack
// (~300-500 cy) every step, delaying its next publishes — and every other
// block's poll waits on the max over publishers, so the whole machine paid
// the tax each step (a different block each time). Now EVERY block writes
// its OWN 4 units (out[t*HID + 4b+w], lane 8 of each wave) at phase D,
// BEFORE the poll, straight from hn: ack drains under the poll flight,
// work is perfectly uniform across blocks. Costs 64B-line false sharing
// on out rows (4 blocks/line) — ≤ +50 MB WRITE vs the 1.06 GB mailbox
// traffic, noise.
// (R8's lesson, reverted: in-flight VMEM latencies OVERLAP at a shared
// waitcnt — pre-draining store acks or deferring the x-prefetch only
// serializes what used to overlap.)
//
// SINGLE-HOP mailbox, 8x replicated. Pair {f32 h, u32 tag=t+1}, one
// global_store_dwordx2 sc0 sc1 per lane (8 B aligned => single-copy
// atomic; tag arrival == data arrival).
// Poll: ONE asm block per round (issue + vmcnt(0) + check) — R1/R3 proved
// split-asm register lifetimes corrupt data; nothing in flight at exit.
//
// Buffering (no S1 => cross-wave LDS needs parity separation):
//  * h_lds[2][.]: A(t) reads h_t from h_lds[p]; H(t) stages h_{t+1} into
//    h_lds[nxt]. Disjoint within an iter; S2 covers cross-iter.
//  * x_lds[2][.]: F(t) reads x_{t+1} from x_lds[nxt] (staged at E(t-1),
//    S2-covered); E(t) writes x_{t+2} into the DEAD buffer x_lds[p].
//    xpre prefetches x_{t+3} at E (R7 position — overlaps poll round 1).
//
// Mailbox parity-2 safety WITHOUT S1: thread tid polls units 4tid..4tid+3
// — i.e. ALL FOUR WAVES of block tid. Any poll success at tag t+1 implies
// every wave of every block passed publish(t+1), hence (program order)
// passed its poll(t) = consumed parity-p tags t. Overwrites (at t+2) thus
// always follow global consumption (at t). Tags monotonic; poll uses >=.
// Workspace: 8*2*1024 u64 = 128 KB, zeroed.
//
// out rows 0..4094: each block writes its own 4 units at D (pre-poll).
// Row 4095 + h_T + c_T: lane 0 of each wave at the final step.
// ---------------------------------------------------------------------------
__global__ __launch_bounds__(256, 1) void lstm_fused(
    const float* __restrict__ x,    // [4096,1024]
    const float* __restrict__ W,    // [1024,4096]
    const float* __restrict__ U,    // [1024,4096]
    const float* __restrict__ bias, // [4096]
    float* __restrict__ out,        // [4096*1024 + 1024 + 1024]
    unsigned long long* __restrict__ pairs) // [8][2][1024] {f32,u32}, zeroed
{
    const int tid  = threadIdx.x;
    const int b    = blockIdx.x;
    const int w    = tid >> 6;      // wave index = unit sub-index
    const int l    = tid & 63;
    const int g    = l & 3;         // gate index (i,f,g,o)
    const int seg  = l >> 2;        // h-segment [64*seg, 64*seg+64)
    const int col  = g * 1024 + b * 4 + w;
    const int unit = b * 4 + w;

    __shared__ __align__(16) float h_lds[2][16 * 68];  // h[k] at [par][ (k>>6)*68 + (k&63) ]
    __shared__ __align__(16) float x_lds[2][16 * 68];
    __shared__ __align__(16) float bias_l[16];         // [g*4 + u]

    float Ureg[64], Wreg[64];
    #pragma unroll
    for (int i = 0; i < 64; ++i) {
        const size_t r = (size_t)(seg * 64 + i) * 4096 + col;
        Ureg[i] = U[r];
        Wreg[i] = W[r];
    }
    if (tid < 16) bias_l[tid] = bias[(tid >> 2) * 1024 + b * 4 + (tid & 3)];

    for (int i = tid; i < 2 * 16 * 68; i += 256) ((float*)h_lds)[i] = 0.0f; // h0 = 0
    const int xofs = (tid >> 4) * 68 + (tid & 15) * 4;  // slot of elems [4tid,4tid+4)
    *(f32x4*)&x_lds[0][xofs] = *(const f32x4*)(x + (size_t)tid * 4);          // x_0
    *(f32x4*)&x_lds[1][xofs] = *(const f32x4*)(x + 1024 + (size_t)tid * 4);   // x_1
    f32x4 xpre = *(const f32x4*)(x + 2048 + (size_t)tid * 4);                 // x_2
    __syncthreads();

    const int hbase = seg * 68;

    // prologue: acc_x = W.x_0 partials (4 independent FMA chains)
    float acc_x;
    {
        float b0 = 0.f, b1 = 0.f, b2 = 0.f, b3 = 0.f;
        #pragma unroll
        for (int i = 0; i < 16; ++i) {
            f32x4 x4 = *(const f32x4*)&x_lds[0][hbase + 4 * i];
            b0 += x4.x * Wreg[4*i];   b1 += x4.y * Wreg[4*i+1];
            b2 += x4.z * Wreg[4*i+2]; b3 += x4.w * Wreg[4*i+3];
        }
        acc_x = (b0 + b1) + (b2 + b3);
    }

    float c_reg = 0.0f;   // cell state of unit (b*4+w), replicated on all lanes

    for (int t = 0; t < T_STEPS; ++t) {
        const int p   = t & 1;
        const int nxt = (t + 1) & 1;

        // A: acc = W.x_t (precomputed) + U.h_t partial
        float acc;
        {
            float a0 = 0.f, a1 = 0.f, a2 = 0.f, a3 = 0.f;
            #pragma unroll
            for (int i = 0; i < 16; ++i) {
                f32x4 h4 = *(const f32x4*)&h_lds[p][hbase + 4 * i];
                a0 += h4.x * Ureg[4*i];   a1 += h4.y * Ureg[4*i+1];
                a2 += h4.z * Ureg[4*i+2]; a3 += h4.w * Ureg[4*i+3];
            }
            acc = acc_x + ((a0 + a1) + (a2 + a3));
        }

        // B: intra-wave reduce over the 16 segs (lanes sharing l&3)
        acc += __shfl_xor(acc, 4);
        acc += __shfl_xor(acc, 8);
        acc += __shfl_xor(acc, 16);
        acc += __shfl_xor(acc, 32);
        // lanes l ≡ g (mod 4) now hold the full sum for gate g

        // C: gates (all 64 lanes, redundant — keeps c_reg wave-replicated)
        const float gi = __shfl(acc, 0) + bias_l[0 + w];
        const float gf = __shfl(acc, 1) + bias_l[4 + w];
        const float gg = __shfl(acc, 2) + bias_l[8 + w];
        const float go = __shfl(acc, 3) + bias_l[12 + w];
        const float iv = 1.0f / (1.0f + __expf(-gi));
        const float fv = 1.0f / (1.0f + __expf(-gf));
        const float tg = 1.0f - 2.0f / (1.0f + __expf(2.0f * gg));
        const float ov = 1.0f / (1.0f + __expf(-go));
        const float cn = fv * c_reg + iv * tg;
        c_reg = cn;
        const float hn = ov * (1.0f - 2.0f / (1.0f + __expf(2.0f * cn)));

        if (t == T_STEPS - 1) {
            if (l == 0) {
                out[(size_t)t * HID + unit] = hn;                 // row 4095
                out[(size_t)T_STEPS * HID + unit] = hn;           // h_T
                out[(size_t)T_STEPS * HID + HID + unit] = cn;     // c_T
            }
            break;
        }

        // D: publish — lane r (r<8) stores unit's pair into replica r;
        //    lane 8 writes the unit's out-row entry (pre-poll, uniform
        //    across blocks: no rotating-writer straggler).
        if (l < NREP) {
            u32x2 pr;
            pr.x = f2u(hn);
            pr.y = (unsigned int)(t + 1);
            unsigned long long* pp = pairs + (size_t)l * 2048
                                   + (size_t)p * 1024 + unit;
            asm volatile("global_store_dwordx2 %0, %1, off sc0 sc1"
                         :: "v"(pp), "v"(pr) : "memory");
        } else if (l == NREP) {
            out[(size_t)t * HID + unit] = hn;
        }

        // E: rotate x: write x_{t+2} into dead buffer x_lds[p]; prefetch
        //    x_{t+3} (R7 position — its flight overlaps poll round 1).
        *(f32x4*)&x_lds[p][xofs] = xpre;
        {
            const int tp3 = (t + 3 < T_STEPS) ? (t + 3) : (T_STEPS - 1);
            xpre = *(const f32x4*)(x + (size_t)tp3 * 1024 + tid * 4);
        }

        // F: acc_x = W.x_{t+1} (overlaps publish flight; reads x_lds[nxt],
        //    staged at E(t-1) and S2-covered)
        {
            float b0 = 0.f, b1 = 0.f, b2 = 0.f, b3 = 0.f;
            #pragma unroll
            for (int i = 0; i < 16; ++i) {
                f32x4 x4 = *(const f32x4*)&x_lds[nxt][hbase + 4 * i];
                b0 += x4.x * Wreg[4*i];   b1 += x4.y * Wreg[4*i+1];
                b2 += x4.z * Wreg[4*i+2]; b3 += x4.w * Wreg[4*i+3];
            }
            acc_x = (b0 + b1) + (b2 + b3);
        }

        // G: poll own 4 pairs (units 4tid..4tid+3) from replica (b & 7).
        //    ONE asm block per round; round 1's vmcnt(0) also drains the
        //    publish/out acks + xpre concurrently (overlap, not sum).
        f32x4 hv4;
        {
            const unsigned int want = (unsigned int)(t + 1);
            const unsigned long long* pp = pairs + (size_t)(b & 7) * 2048
                                         + (size_t)p * 1024 + tid * 4;
            u32x4 q0, q1;
            for (;;) {
                asm volatile("global_load_dwordx4 %0, %2, off sc0 sc1\n\t"
                             "global_load_dwordx4 %1, %3, off sc0 sc1\n\t"
                             "s_waitcnt vmcnt(0)"
                             : "=&v"(q0), "=&v"(q1)
                             : "v"(pp), "v"(pp + 2) : "memory");
                if (q0.y >= want && q0.w >= want && q1.y >= want && q1.w >= want)
                    break;
            }
            hv4.x = u2f(q0.x); hv4.y = u2f(q0.z);
            hv4.z = u2f(q1.x); hv4.w = u2f(q1.z);
        }

        // H: stage h_{t+1} for next step's A
        *(f32x4*)&h_lds[nxt][xofs] = hv4;

        __syncthreads();   // [S2] h_lds[nxt] + x_lds[p] staged (ONLY barrier)
    }
}

extern "C" void kernel_launch(void* const* d_in, const int* in_sizes, int n_in,
                              void* d_out, int out_size, void* d_ws, size_t ws_size,
                              hipStream_t stream) {
    const float* x    = (const float*)d_in[0];
    const float* W    = (const float*)d_in[1];
    const float* U    = (const float*)d_in[2];
    const float* bias = (const float*)d_in[3];
    float* out = (float*)d_out;

    // Workspace: pairs[8][2][1024] x 8 B = 128 KB @ +0 (zeroed: tag fields
    // must start below 1; re-poisoned 0xAA would read as huge tags).
    unsigned long long* pairs = (unsigned long long*)d_ws;

    hipMemsetAsync(pairs, 0, (size_t)NREP * 2 * 1024 * sizeof(unsigned long long), stream);
    lstm_fused<<<NBLK, 256, 0, stream>>>(x, W, U, bias, out, pairs);
}

// Round 10
// 7061.735 us; speedup vs baseline: 1.0878x; 1.0182x over previous
//
#include <hip/hip_runtime.h>
#include <stdint.h>

typedef __attribute__((ext_vector_type(4))) float f32x4;
typedef __attribute__((ext_vector_type(2))) unsigned int u32x2;
typedef __attribute__((ext_vector_type(4))) unsigned int u32x4;

#define T_STEPS 4096
#define HID 1024
#define NBLK 256
#define NREP 8          // mailbox replicas (R5-proven knee; 16 regressed)

static __device__ __forceinline__ float u2f(unsigned int u) {
    union { float f; unsigned int i; } c; c.i = u; return c.f;
}
static __device__ __forceinline__ unsigned int f2u(float f) {
    union { float f; unsigned int i; } c; c.f = f; return c.i;
}

// ---------------------------------------------------------------------------
// Fully fused persistent LSTM, fp32. 256 blocks x 256 threads, 1 block/CU.
//
// Structure (R7/R9, 7.15 ms): PER-WAVE UNITS + INTRA-WAVE REDUCE.
// Wave w of block b owns hidden unit (b*4+w) = all 4 gate columns
//   col(g) = g*1024 + b*4 + w.  Lane l: g = l&3, seg = l>>2;
//   thread holds U/W[64*seg .. +64)[col(g)] in VGPRs (64 each).
// Cross-column reduction: 4x shfl_xor — no red[] LDS, no S1. One barrier
// per step (S2). All 4 waves compute gates & publish their own unit in
// parallel: lanes 0-7 -> 8 replicas; lane 8 writes the unit's out entry.
//
// R10 vs R9 — ONE change: mailbox scope SYSTEM (sc0 sc1) -> DEVICE (sc1).
// Counter evidence: FETCH 328 MB = 48 MB ideal (W/U/x) + ~280 MB extra
// ~= 1070 HBM lines/step = the poll working set; WRITE 1.08 GB = mailbox
// lines written through to HBM ~4x/step. The 128 KB mailbox should be
// LLC-resident; system-scope ops appear to be serviced at the SYSTEM
// coherence point (HBM, ~900 cy RT) instead of the MALL (~500 cy).
// Device scope is sufficient: all readers are on-device (cross-XCD only
// needs the device coherence point), and R2 already validated sc1-only
// correctness on this hardware. If the theory holds, every poll RT and
// publish-visibility hop shortens by ~400 cy.
//
// SINGLE-HOP mailbox, 8x replicated. Pair {f32 h, u32 tag=t+1}, one
// global_store_dwordx2 sc1 per lane (8 B aligned => single-copy atomic;
// tag arrival == data arrival).
// Poll: ONE asm block per round (issue + vmcnt(0) + check) — R1/R3 proved
// split-asm register lifetimes corrupt data; nothing in flight at exit.
// R8 lesson (reverted there): in-flight VMEM latencies OVERLAP at a shared
// waitcnt — do not pre-drain store acks, do not defer the x-prefetch.
//
// Buffering (no S1 => cross-wave LDS needs parity separation):
//  * h_lds[2][.]: A(t) reads h_t from h_lds[p]; H(t) stages h_{t+1} into
//    h_lds[nxt]. Disjoint within an iter; S2 covers cross-iter.
//  * x_lds[2][.]: F(t) reads x_{t+1} from x_lds[nxt] (staged at E(t-1),
//    S2-covered); E(t) writes x_{t+2} into the DEAD buffer x_lds[p].
//    xpre prefetches x_{t+3} at E (overlaps poll round 1).
//
// Mailbox parity-2 safety WITHOUT S1: thread tid polls units 4tid..4tid+3
// — i.e. ALL FOUR WAVES of block tid. Any poll success at tag t+1 implies
// every wave of every block passed publish(t+1), hence (program order)
// passed its poll(t) = consumed parity-p tags t. Overwrites (at t+2) thus
// always follow global consumption (at t). Tags monotonic; poll uses >=.
// Workspace: 8*2*1024 u64 = 128 KB, zeroed.
// ---------------------------------------------------------------------------
__global__ __launch_bounds__(256, 1) void lstm_fused(
    const float* __restrict__ x,    // [4096,1024]
    const float* __restrict__ W,    // [1024,4096]
    const float* __restrict__ U,    // [1024,4096]
    const float* __restrict__ bias, // [4096]
    float* __restrict__ out,        // [4096*1024 + 1024 + 1024]
    unsigned long long* __restrict__ pairs) // [8][2][1024] {f32,u32}, zeroed
{
    const int tid  = threadIdx.x;
    const int b    = blockIdx.x;
    const int w    = tid >> 6;      // wave index = unit sub-index
    const int l    = tid & 63;
    const int g    = l & 3;         // gate index (i,f,g,o)
    const int seg  = l >> 2;        // h-segment [64*seg, 64*seg+64)
    const int col  = g * 1024 + b * 4 + w;
    const int unit = b * 4 + w;

    __shared__ __align__(16) float h_lds[2][16 * 68];  // h[k] at [par][ (k>>6)*68 + (k&63) ]
    __shared__ __align__(16) float x_lds[2][16 * 68];
    __shared__ __align__(16) float bias_l[16];         // [g*4 + u]

    float Ureg[64], Wreg[64];
    #pragma unroll
    for (int i = 0; i < 64; ++i) {
        const size_t r = (size_t)(seg * 64 + i) * 4096 + col;
        Ureg[i] = U[r];
        Wreg[i] = W[r];
    }
    if (tid < 16) bias_l[tid] = bias[(tid >> 2) * 1024 + b * 4 + (tid & 3)];

    for (int i = tid; i < 2 * 16 * 68; i += 256) ((float*)h_lds)[i] = 0.0f; // h0 = 0
    const int xofs = (tid >> 4) * 68 + (tid & 15) * 4;  // slot of elems [4tid,4tid+4)
    *(f32x4*)&x_lds[0][xofs] = *(const f32x4*)(x + (size_t)tid * 4);          // x_0
    *(f32x4*)&x_lds[1][xofs] = *(const f32x4*)(x + 1024 + (size_t)tid * 4);   // x_1
    f32x4 xpre = *(const f32x4*)(x + 2048 + (size_t)tid * 4);                 // x_2
    __syncthreads();

    const int hbase = seg * 68;

    // prologue: acc_x = W.x_0 partials (4 independent FMA chains)
    float acc_x;
    {
        float b0 = 0.f, b1 = 0.f, b2 = 0.f, b3 = 0.f;
        #pragma unroll
        for (int i = 0; i < 16; ++i) {
            f32x4 x4 = *(const f32x4*)&x_lds[0][hbase + 4 * i];
            b0 += x4.x * Wreg[4*i];   b1 += x4.y * Wreg[4*i+1];
            b2 += x4.z * Wreg[4*i+2]; b3 += x4.w * Wreg[4*i+3];
        }
        acc_x = (b0 + b1) + (b2 + b3);
    }

    float c_reg = 0.0f;   // cell state of unit (b*4+w), replicated on all lanes

    for (int t = 0; t < T_STEPS; ++t) {
        const int p   = t & 1;
        const int nxt = (t + 1) & 1;

        // A: acc = W.x_t (precomputed) + U.h_t partial
        float acc;
        {
            float a0 = 0.f, a1 = 0.f, a2 = 0.f, a3 = 0.f;
            #pragma unroll
            for (int i = 0; i < 16; ++i) {
                f32x4 h4 = *(const f32x4*)&h_lds[p][hbase + 4 * i];
                a0 += h4.x * Ureg[4*i];   a1 += h4.y * Ureg[4*i+1];
                a2 += h4.z * Ureg[4*i+2]; a3 += h4.w * Ureg[4*i+3];
            }
            acc = acc_x + ((a0 + a1) + (a2 + a3));
        }

        // B: intra-wave reduce over the 16 segs (lanes sharing l&3)
        acc += __shfl_xor(acc, 4);
        acc += __shfl_xor(acc, 8);
        acc += __shfl_xor(acc, 16);
        acc += __shfl_xor(acc, 32);
        // lanes l ≡ g (mod 4) now hold the full sum for gate g

        // C: gates (all 64 lanes, redundant — keeps c_reg wave-replicated)
        const float gi = __shfl(acc, 0) + bias_l[0 + w];
        const float gf = __shfl(acc, 1) + bias_l[4 + w];
        const float gg = __shfl(acc, 2) + bias_l[8 + w];
        const float go = __shfl(acc, 3) + bias_l[12 + w];
        const float iv = 1.0f / (1.0f + __expf(-gi));
        const float fv = 1.0f / (1.0f + __expf(-gf));
        const float tg = 1.0f - 2.0f / (1.0f + __expf(2.0f * gg));
        const float ov = 1.0f / (1.0f + __expf(-go));
        const float cn = fv * c_reg + iv * tg;
        c_reg = cn;
        const float hn = ov * (1.0f - 2.0f / (1.0f + __expf(2.0f * cn)));

        if (t == T_STEPS - 1) {
            if (l == 0) {
                out[(size_t)t * HID + unit] = hn;                 // row 4095
                out[(size_t)T_STEPS * HID + unit] = hn;           // h_T
                out[(size_t)T_STEPS * HID + HID + unit] = cn;     // c_T
            }
            break;
        }

        // D: publish — lane r (r<8) stores unit's pair into replica r
        //    (DEVICE scope sc1); lane 8 writes the unit's out-row entry.
        if (l < NREP) {
            u32x2 pr;
            pr.x = f2u(hn);
            pr.y = (unsigned int)(t + 1);
            unsigned long long* pp = pairs + (size_t)l * 2048
                                   + (size_t)p * 1024 + unit;
            asm volatile("global_store_dwordx2 %0, %1, off sc1"
                         :: "v"(pp), "v"(pr) : "memory");
        } else if (l == NREP) {
            out[(size_t)t * HID + unit] = hn;
        }

        // E: rotate x: write x_{t+2} into dead buffer x_lds[p]; prefetch
        //    x_{t+3} (its flight overlaps poll round 1).
        *(f32x4*)&x_lds[p][xofs] = xpre;
        {
            const int tp3 = (t + 3 < T_STEPS) ? (t + 3) : (T_STEPS - 1);
            xpre = *(const f32x4*)(x + (size_t)tp3 * 1024 + tid * 4);
        }

        // F: acc_x = W.x_{t+1} (overlaps publish flight; reads x_lds[nxt],
        //    staged at E(t-1) and S2-covered)
        {
            float b0 = 0.f, b1 = 0.f, b2 = 0.f, b3 = 0.f;
            #pragma unroll
            for (int i = 0; i < 16; ++i) {
                f32x4 x4 = *(const f32x4*)&x_lds[nxt][hbase + 4 * i];
                b0 += x4.x * Wreg[4*i];   b1 += x4.y * Wreg[4*i+1];
                b2 += x4.z * Wreg[4*i+2]; b3 += x4.w * Wreg[4*i+3];
            }
            acc_x = (b0 + b1) + (b2 + b3);
        }

        // G: poll own 4 pairs (units 4tid..4tid+3) from replica (b & 7),
        //    DEVICE scope sc1. ONE asm block per round; round 1's vmcnt(0)
        //    drains publish/out acks + xpre concurrently (overlap, not sum).
        f32x4 hv4;
        {
            const unsigned int want = (unsigned int)(t + 1);
            const unsigned long long* pp = pairs + (size_t)(b & 7) * 2048
                                         + (size_t)p * 1024 + tid * 4;
            u32x4 q0, q1;
            for (;;) {
                asm volatile("global_load_dwordx4 %0, %2, off sc1\n\t"
                             "global_load_dwordx4 %1, %3, off sc1\n\t"
                             "s_waitcnt vmcnt(0)"
                             : "=&v"(q0), "=&v"(q1)
                             : "v"(pp), "v"(pp + 2) : "memory");
                if (q0.y >= want && q0.w >= want && q1.y >= want && q1.w >= want)
                    break;
            }
            hv4.x = u2f(q0.x); hv4.y = u2f(q0.z);
            hv4.z = u2f(q1.x); hv4.w = u2f(q1.z);
        }

        // H: stage h_{t+1} for next step's A
        *(f32x4*)&h_lds[nxt][xofs] = hv4;

        __syncthreads();   // [S2] h_lds[nxt] + x_lds[p] staged (ONLY barrier)
    }
}

extern "C" void kernel_launch(void* const* d_in, const int* in_sizes, int n_in,
                              void* d_out, int out_size, void* d_ws, size_t ws_size,
                              hipStream_t stream) {
    const float* x    = (const float*)d_in[0];
    const float* W    = (const float*)d_in[1];
    const float* U    = (const float*)d_in[2];
    const float* bias = (const float*)d_in[3];
    float* out = (float*)d_out;

    // Workspace: pairs[8][2][1024] x 8 B = 128 KB @ +0 (zeroed: tag fields
    // must start below 1; re-poisoned 0xAA would read as huge tags).
    unsigned long long* pairs = (unsigned long long*)d_ws;

    hipMemsetAsync(pairs, 0, (size_t)NREP * 2 * 1024 * sizeof(unsigned long long), stream);
    lstm_fused<<<NBLK, 256, 0, stream>>>(x, W, U, bias, out, pairs);
}